// Round 4
// baseline (2862.008 us; speedup 1.0000x reference)
//
#include <hip/hip_runtime.h>
#include <math.h>

#define NE 1000000
#define DD 128
#define TWOD 256
#define H1C 256
#define H2C 128
#define EB 32            // 8 edges per wave, 4 waves, fully wave-independent
#define EPSLN 1e-5f

typedef float f32x2 __attribute__((ext_vector_type(2)));
typedef float f32x4 __attribute__((ext_vector_type(4)));

#define LO2(q) __builtin_shufflevector((q), (q), 0, 1)
#define HI2(q) __builtin_shufflevector((q), (q), 2, 3)

// c += broadcast(x.lo) * w
__device__ __forceinline__ void pk_fma_b0(f32x2& c, f32x2 x, f32x2 w) {
    asm("v_pk_fma_f32 %0, %1, %2, %0 op_sel:[0,0,0] op_sel_hi:[0,1,1]"
        : "+v"(c) : "v"(x), "v"(w));
}
// c += broadcast(x.hi) * w
__device__ __forceinline__ void pk_fma_b1(f32x2& c, f32x2 x, f32x2 w) {
    asm("v_pk_fma_f32 %0, %1, %2, %0 op_sel:[1,0,0] op_sel_hi:[1,1,1]"
        : "+v"(c) : "v"(x), "v"(w));
}

__global__ __launch_bounds__(256, 4)
void decoder_fused(const float* __restrict__ nodes,
                   const float* __restrict__ nbrs,
                   const int*   __restrict__ eidx,
                   const float* __restrict__ g0, const float* __restrict__ be0,
                   const float* __restrict__ W1, const float* __restrict__ b1,
                   const float* __restrict__ g1, const float* __restrict__ be1,
                   const float* __restrict__ W2, const float* __restrict__ b2,
                   const float* __restrict__ g2, const float* __restrict__ be2,
                   const float* __restrict__ Wp, const float* __restrict__ bp,
                   const float* __restrict__ Ww, const float* __restrict__ bw,
                   const float* __restrict__ wnode, const float* __restrict__ wnbr,
                   float* __restrict__ out)
{
    __shared__ __align__(16) float xb[EB][TWOD];   // 32 KB; rows wv*8..wv*8+7 private to wave wv
    __shared__ float nbsim[EB];

    const int t    = threadIdx.x;
    const int wv   = t >> 6;     // wave 0..3
    const int lane = t & 63;
    const int e0   = blockIdx.x * EB;
    const int r0   = wv * 8;     // this wave's 8 rows/edges

    // ---------------- Stage 1: gather + combined + LN0 + nbrs_sim (8 edges) --
    {
        const int c = 2 * lane;
        const float2 g0s  = *(const float2*)(g0  + c);
        const float2 g0p  = *(const float2*)(g0  + DD + c);
        const float2 be0s = *(const float2*)(be0 + c);
        const float2 be0p = *(const float2*)(be0 + DD + c);
        #pragma unroll 2
        for (int ee = 0; ee < 8; ++ee) {
            const int el = r0 + ee;
            const int e  = e0 + el;
            const int u  = eidx[e];
            const int v  = eidx[NE + e];
            const float2 nu = *(const float2*)(nodes + u * DD + c);
            const float2 nv = *(const float2*)(nodes + v * DD + c);
            const float2 bu = *(const float2*)(nbrs  + u * DD + c);
            const float2 bv = *(const float2*)(nbrs  + v * DD + c);
            const float sx = nu.x + nv.x, sy = nu.y + nv.y;
            const float px = nu.x * nv.x, py = nu.y * nv.y;
            float ps  = sx + sy + px + py;
            float pss = sx*sx + sy*sy + px*px + py*py;
            float pd  = bu.x * bv.x + bu.y * bv.y;
            #pragma unroll
            for (int m = 1; m < 64; m <<= 1) {
                ps  += __shfl_xor(ps,  m, 64);
                pss += __shfl_xor(pss, m, 64);
                pd  += __shfl_xor(pd,  m, 64);
            }
            const float mu  = ps  * (1.0f / 256.0f);
            const float var = pss * (1.0f / 256.0f) - mu * mu;
            const float inv = 1.0f / sqrtf(var + EPSLN);
            *(float2*)&xb[el][c]      = make_float2((sx - mu) * inv * g0s.x + be0s.x,
                                                    (sy - mu) * inv * g0s.y + be0s.y);
            *(float2*)&xb[el][DD + c] = make_float2((px - mu) * inv * g0p.x + be0p.x,
                                                    (py - mu) * inv * g0p.y + be0p.y);
            if (lane == 0) nbsim[el] = pd;
        }
    }
    // no __syncthreads: all xb rows used below belong to this wave

    // ---------------- GEMM1: 8 rows x 4 cols/lane (2 col-pairs) --------------
    f32x2 acc1[8][2];
    #pragma unroll
    for (int i = 0; i < 8; ++i) {
        acc1[i][0] = f32x2{0.0f, 0.0f};
        acc1[i][1] = f32x2{0.0f, 0.0f};
    }

    const int c1 = lane * 4;
    {
        const float* __restrict__ w1p = W1 + c1;
        f32x4 cw0 = *(const f32x4*)(w1p);
        f32x4 cw1 = *(const f32x4*)(w1p + H1C);
        f32x4 cw2 = *(const f32x4*)(w1p + 2 * H1C);
        f32x4 cw3 = *(const f32x4*)(w1p + 3 * H1C);

        #pragma unroll 2
        for (int k0 = 0; k0 < TWOD; k0 += 4) {
            f32x2 xp0[8], xp1[8];
            #pragma unroll
            for (int i = 0; i < 8; ++i) {
                f32x4 q = *(const f32x4*)&xb[r0 + i][k0];
                xp0[i] = LO2(q); xp1[i] = HI2(q);
            }
            const int kn = (k0 + 4) & 255;   // cyclic: last prefetch harmless
            const float* wnp = w1p + kn * H1C;
            f32x4 nw0 = *(const f32x4*)(wnp);
            f32x4 nw1 = *(const f32x4*)(wnp + H1C);
            f32x4 nw2 = *(const f32x4*)(wnp + 2 * H1C);
            f32x4 nw3 = *(const f32x4*)(wnp + 3 * H1C);

            f32x2 wA, wB;
            wA = LO2(cw0); wB = HI2(cw0);
            #pragma unroll
            for (int i = 0; i < 8; ++i) {
                pk_fma_b0(acc1[i][0], xp0[i], wA);
                pk_fma_b0(acc1[i][1], xp0[i], wB);
            }
            wA = LO2(cw1); wB = HI2(cw1);
            #pragma unroll
            for (int i = 0; i < 8; ++i) {
                pk_fma_b1(acc1[i][0], xp0[i], wA);
                pk_fma_b1(acc1[i][1], xp0[i], wB);
            }
            wA = LO2(cw2); wB = HI2(cw2);
            #pragma unroll
            for (int i = 0; i < 8; ++i) {
                pk_fma_b0(acc1[i][0], xp1[i], wA);
                pk_fma_b0(acc1[i][1], xp1[i], wB);
            }
            wA = LO2(cw3); wB = HI2(cw3);
            #pragma unroll
            for (int i = 0; i < 8; ++i) {
                pk_fma_b1(acc1[i][0], xp1[i], wA);
                pk_fma_b1(acc1[i][1], xp1[i], wB);
            }
            cw0 = nw0; cw1 = nw1; cw2 = nw2; cw3 = nw3;
        }
    }

    // ---------------- bias + LN1 + ReLU, write h1 back (own rows only) -------
    {
        const float4 b1v = *(const float4*)(b1  + c1);
        const float4 g1v = *(const float4*)(g1  + c1);
        const float4 e1v = *(const float4*)(be1 + c1);
        #pragma unroll
        for (int i = 0; i < 8; ++i) {
            float v0 = acc1[i][0].x + b1v.x;
            float v1 = acc1[i][0].y + b1v.y;
            float v2 = acc1[i][1].x + b1v.z;
            float v3 = acc1[i][1].y + b1v.w;
            float s  = (v0 + v1) + (v2 + v3);
            float ss = (v0*v0 + v1*v1) + (v2*v2 + v3*v3);
            #pragma unroll
            for (int m = 1; m < 64; m <<= 1) {
                s  += __shfl_xor(s,  m, 64);
                ss += __shfl_xor(ss, m, 64);
            }
            const float mu  = s  * (1.0f / 256.0f);
            const float var = ss * (1.0f / 256.0f) - mu * mu;
            const float inv = 1.0f / sqrtf(var + EPSLN);
            float o0 = fmaxf(0.0f, (v0-mu)*inv*g1v.x + e1v.x);
            float o1 = fmaxf(0.0f, (v1-mu)*inv*g1v.y + e1v.y);
            float o2 = fmaxf(0.0f, (v2-mu)*inv*g1v.z + e1v.z);
            float o3 = fmaxf(0.0f, (v3-mu)*inv*g1v.w + e1v.w);
            *(float4*)&xb[r0 + i][c1] = make_float4(o0, o1, o2, o3);
        }
    }
    // no __syncthreads: h1 rows consumed only by this wave

    // ---------------- GEMM2: 8 rows x 2 cols/lane ----------------------------
    f32x2 acc2[8];
    #pragma unroll
    for (int i = 0; i < 8; ++i) acc2[i] = f32x2{0.0f, 0.0f};

    const int c2 = lane * 2;
    {
        const float* __restrict__ w2p = W2 + c2;
        f32x2 d0 = *(const f32x2*)(w2p);
        f32x2 d1 = *(const f32x2*)(w2p + H2C);
        f32x2 d2 = *(const f32x2*)(w2p + 2 * H2C);
        f32x2 d3 = *(const f32x2*)(w2p + 3 * H2C);

        #pragma unroll 2
        for (int k0 = 0; k0 < TWOD; k0 += 4) {
            f32x2 xp0[8], xp1[8];
            #pragma unroll
            for (int i = 0; i < 8; ++i) {
                f32x4 q = *(const f32x4*)&xb[r0 + i][k0];
                xp0[i] = LO2(q); xp1[i] = HI2(q);
            }
            const int kn = (k0 + 4) & 255;
            const float* wnp = w2p + kn * H2C;
            f32x2 m0 = *(const f32x2*)(wnp);
            f32x2 m1 = *(const f32x2*)(wnp + H2C);
            f32x2 m2 = *(const f32x2*)(wnp + 2 * H2C);
            f32x2 m3 = *(const f32x2*)(wnp + 3 * H2C);

            #pragma unroll
            for (int i = 0; i < 8; ++i) pk_fma_b0(acc2[i], xp0[i], d0);
            #pragma unroll
            for (int i = 0; i < 8; ++i) pk_fma_b1(acc2[i], xp0[i], d1);
            #pragma unroll
            for (int i = 0; i < 8; ++i) pk_fma_b0(acc2[i], xp1[i], d2);
            #pragma unroll
            for (int i = 0; i < 8; ++i) pk_fma_b1(acc2[i], xp1[i], d3);
            d0 = m0; d1 = m1; d2 = m2; d3 = m3;
        }
    }

    // ---------------- bias + LN2 + ReLU + heads + outputs --------------------
    {
        const float2 b2v = *(const float2*)(b2  + c2);
        const float2 g2v = *(const float2*)(g2  + c2);
        const float2 e2v = *(const float2*)(be2 + c2);
        const float2 wpv = *(const float2*)(Wp  + c2);
        const float2 wwv = *(const float2*)(Ww  + c2);
        const float ww128 = Ww[DD];
        const float bpv = bp[0], bwv = bw[0];
        const float wn = wnode[0], wbr = wnbr[0];
        #pragma unroll
        for (int i = 0; i < 8; ++i) {
            const float v0 = acc2[i].x + b2v.x;
            const float v1 = acc2[i].y + b2v.y;
            float s  = v0 + v1;
            float ss = v0*v0 + v1*v1;
            #pragma unroll
            for (int m = 1; m < 64; m <<= 1) {
                s  += __shfl_xor(s,  m, 64);
                ss += __shfl_xor(ss, m, 64);
            }
            const float mu  = s  * (1.0f / 128.0f);
            const float var = ss * (1.0f / 128.0f) - mu * mu;
            const float inv = 1.0f / sqrtf(var + EPSLN);
            const float h0 = fmaxf(0.0f, (v0-mu)*inv*g2v.x + e2v.x);
            const float h1 = fmaxf(0.0f, (v1-mu)*inv*g2v.y + e2v.y);
            float pdot = h0 * wpv.x + h1 * wpv.y;
            float wdot = h0 * wwv.x + h1 * wwv.y;
            #pragma unroll
            for (int m = 1; m < 64; m <<= 1) {
                pdot += __shfl_xor(pdot, m, 64);
                wdot += __shfl_xor(wdot, m, 64);
            }
            if (lane == 0) {
                const int e  = e0 + r0 + i;
                const float ns   = nbsim[r0 + i];
                const float nc   = (pdot + bpv) * wn;
                const float nbc  = ns * wbr;
                const float prob = nc + nbc;
                out[e]          = prob;
                out[NE + e]     = fmaxf(0.0f, wdot + ns * ww128 + bwv);
                out[2 * NE + e] = nc / (prob + 1e-8f);
            }
        }
    }
}

extern "C" void kernel_launch(void* const* d_in, const int* in_sizes, int n_in,
                              void* d_out, int out_size, void* d_ws, size_t ws_size,
                              hipStream_t stream) {
    const float* nodes = (const float*)d_in[0];
    const float* nbrs  = (const float*)d_in[1];
    const int*   eidx  = (const int*)d_in[2];
    const float* g0    = (const float*)d_in[3];
    const float* be0   = (const float*)d_in[4];
    const float* W1    = (const float*)d_in[5];
    const float* b1    = (const float*)d_in[6];
    const float* g1    = (const float*)d_in[7];
    const float* be1   = (const float*)d_in[8];
    const float* W2    = (const float*)d_in[9];
    const float* b2    = (const float*)d_in[10];
    const float* g2    = (const float*)d_in[11];
    const float* be2   = (const float*)d_in[12];
    const float* Wp    = (const float*)d_in[13];
    const float* bp    = (const float*)d_in[14];
    const float* Ww    = (const float*)d_in[15];
    const float* bw    = (const float*)d_in[16];
    const float* wnode = (const float*)d_in[17];
    const float* wnbr  = (const float*)d_in[18];
    float* out = (float*)d_out;

    dim3 grid(NE / EB), block(256);
    decoder_fused<<<grid, block, 0, stream>>>(nodes, nbrs, eidx, g0, be0,
                                              W1, b1, g1, be1, W2, b2, g2, be2,
                                              Wp, bp, Ww, bw, wnode, wnbr, out);
}

// Round 5
// 2670.974 us; speedup vs baseline: 1.0715x; 1.0715x over previous
//
#include <hip/hip_runtime.h>
#include <math.h>

#define NE 1000000
#define DD 128
#define TWOD 256
#define H1C 256
#define H2C 128
#define EB 64            // 16 edges per wave, wave-private rows: NO block barriers
#define EPSLN 1e-5f

typedef float f32x2 __attribute__((ext_vector_type(2)));
typedef float f32x4 __attribute__((ext_vector_type(4)));

#define LO2(q) __builtin_shufflevector((q), (q), 0, 1)
#define HI2(q) __builtin_shufflevector((q), (q), 2, 3)

// c += broadcast(x.lo) * w
__device__ __forceinline__ void pk_fma_b0(f32x2& c, f32x2 x, f32x2 w) {
    asm("v_pk_fma_f32 %0, %1, %2, %0 op_sel:[0,0,0] op_sel_hi:[0,1,1]"
        : "+v"(c) : "v"(x), "v"(w));
}
// c += broadcast(x.hi) * w
__device__ __forceinline__ void pk_fma_b1(f32x2& c, f32x2 x, f32x2 w) {
    asm("v_pk_fma_f32 %0, %1, %2, %0 op_sel:[1,0,0] op_sel_hi:[1,1,1]"
        : "+v"(c) : "v"(x), "v"(w));
}

// ---- GEMM1 helpers: 8 rows x 8 cols per thread, k-chunk of 4 ---------------
#define G1_PREF(X, WW, K) do {                                                 \
    const int kq_ = (K) & 255;                                                 \
    _Pragma("unroll") for (int i_ = 0; i_ < 8; ++i_)                           \
        X[i_] = *(const f32x4*)&xb[r0 + i_][kq_];                              \
    const float* wp_ = w1p + kq_ * H1C;                                        \
    WW[0] = *(const f32x4*)(wp_);                                              \
    WW[1] = *(const f32x4*)(wp_ + 4);                                          \
    WW[2] = *(const f32x4*)(wp_ + H1C);                                        \
    WW[3] = *(const f32x4*)(wp_ + H1C + 4);                                    \
    WW[4] = *(const f32x4*)(wp_ + 2 * H1C);                                    \
    WW[5] = *(const f32x4*)(wp_ + 2 * H1C + 4);                                \
    WW[6] = *(const f32x4*)(wp_ + 3 * H1C);                                    \
    WW[7] = *(const f32x4*)(wp_ + 3 * H1C + 4);                                \
} while (0)

#define G1_FMA(X, WW) do {                                                     \
    f32x2 wA_, wB_, wC_, wD_;                                                  \
    wA_ = LO2(WW[0]); wB_ = HI2(WW[0]); wC_ = LO2(WW[1]); wD_ = HI2(WW[1]);    \
    _Pragma("unroll") for (int i_ = 0; i_ < 8; ++i_) {                         \
        f32x2 xl_ = LO2(X[i_]);                                                \
        pk_fma_b0(acc1[i_][0], xl_, wA_); pk_fma_b0(acc1[i_][1], xl_, wB_);    \
        pk_fma_b0(acc1[i_][2], xl_, wC_); pk_fma_b0(acc1[i_][3], xl_, wD_); }  \
    wA_ = LO2(WW[2]); wB_ = HI2(WW[2]); wC_ = LO2(WW[3]); wD_ = HI2(WW[3]);    \
    _Pragma("unroll") for (int i_ = 0; i_ < 8; ++i_) {                         \
        f32x2 xl_ = LO2(X[i_]);                                                \
        pk_fma_b1(acc1[i_][0], xl_, wA_); pk_fma_b1(acc1[i_][1], xl_, wB_);    \
        pk_fma_b1(acc1[i_][2], xl_, wC_); pk_fma_b1(acc1[i_][3], xl_, wD_); }  \
    wA_ = LO2(WW[4]); wB_ = HI2(WW[4]); wC_ = LO2(WW[5]); wD_ = HI2(WW[5]);    \
    _Pragma("unroll") for (int i_ = 0; i_ < 8; ++i_) {                         \
        f32x2 xh_ = HI2(X[i_]);                                                \
        pk_fma_b0(acc1[i_][0], xh_, wA_); pk_fma_b0(acc1[i_][1], xh_, wB_);    \
        pk_fma_b0(acc1[i_][2], xh_, wC_); pk_fma_b0(acc1[i_][3], xh_, wD_); }  \
    wA_ = LO2(WW[6]); wB_ = HI2(WW[6]); wC_ = LO2(WW[7]); wD_ = HI2(WW[7]);    \
    _Pragma("unroll") for (int i_ = 0; i_ < 8; ++i_) {                         \
        f32x2 xh_ = HI2(X[i_]);                                                \
        pk_fma_b1(acc1[i_][0], xh_, wA_); pk_fma_b1(acc1[i_][1], xh_, wB_);    \
        pk_fma_b1(acc1[i_][2], xh_, wC_); pk_fma_b1(acc1[i_][3], xh_, wD_); }  \
} while (0)

// ---- GEMM2 helpers: 8 rows x 4 cols per thread -----------------------------
#define G2_PREF(X, WW, K) do {                                                 \
    const int kq_ = (K) & 255;                                                 \
    _Pragma("unroll") for (int i_ = 0; i_ < 8; ++i_)                           \
        X[i_] = *(const f32x4*)&xb[r0 + i_][kq_];                              \
    const float* wp_ = w2p + kq_ * H2C;                                        \
    WW[0] = *(const f32x4*)(wp_);                                              \
    WW[1] = *(const f32x4*)(wp_ + H2C);                                        \
    WW[2] = *(const f32x4*)(wp_ + 2 * H2C);                                    \
    WW[3] = *(const f32x4*)(wp_ + 3 * H2C);                                    \
} while (0)

#define G2_FMA(X, WW) do {                                                     \
    f32x2 wA_, wB_;                                                            \
    wA_ = LO2(WW[0]); wB_ = HI2(WW[0]);                                        \
    _Pragma("unroll") for (int i_ = 0; i_ < 8; ++i_) {                         \
        f32x2 xl_ = LO2(X[i_]);                                                \
        pk_fma_b0(acc2[i_][0], xl_, wA_); pk_fma_b0(acc2[i_][1], xl_, wB_); }  \
    wA_ = LO2(WW[1]); wB_ = HI2(WW[1]);                                        \
    _Pragma("unroll") for (int i_ = 0; i_ < 8; ++i_) {                         \
        f32x2 xl_ = LO2(X[i_]);                                                \
        pk_fma_b1(acc2[i_][0], xl_, wA_); pk_fma_b1(acc2[i_][1], xl_, wB_); }  \
    wA_ = LO2(WW[2]); wB_ = HI2(WW[2]);                                        \
    _Pragma("unroll") for (int i_ = 0; i_ < 8; ++i_) {                         \
        f32x2 xh_ = HI2(X[i_]);                                                \
        pk_fma_b0(acc2[i_][0], xh_, wA_); pk_fma_b0(acc2[i_][1], xh_, wB_); }  \
    wA_ = LO2(WW[3]); wB_ = HI2(WW[3]);                                        \
    _Pragma("unroll") for (int i_ = 0; i_ < 8; ++i_) {                         \
        f32x2 xh_ = HI2(X[i_]);                                                \
        pk_fma_b1(acc2[i_][0], xh_, wA_); pk_fma_b1(acc2[i_][1], xh_, wB_); }  \
} while (0)

__global__ __launch_bounds__(256, 2)
void decoder_fused(const float* __restrict__ nodes,
                   const float* __restrict__ nbrs,
                   const int*   __restrict__ eidx,
                   const float* __restrict__ g0, const float* __restrict__ be0,
                   const float* __restrict__ W1, const float* __restrict__ b1,
                   const float* __restrict__ g1, const float* __restrict__ be1,
                   const float* __restrict__ W2, const float* __restrict__ b2,
                   const float* __restrict__ g2, const float* __restrict__ be2,
                   const float* __restrict__ Wp, const float* __restrict__ bp,
                   const float* __restrict__ Ww, const float* __restrict__ bw,
                   const float* __restrict__ wnode, const float* __restrict__ wnbr,
                   float* __restrict__ out)
{
    __shared__ __align__(16) float xb[EB][TWOD];   // 64 KB; rows 16wv..16wv+15 private to wave wv
    __shared__ float nbsim[EB];

    const int t    = threadIdx.x;
    const int wv   = t >> 6;     // wave 0..3
    const int lane = t & 63;
    const int cb   = lane & 31;  // col block 0..31
    const int e0   = blockIdx.x * EB;
    const int r0   = wv * 16 + (lane >> 5) * 8;   // this thread's 8 rows

    // ---------------- Stage 1: gather + combined + LN0 + nbrs_sim ------------
    {
        const int c = 2 * lane;
        const float2 g0s  = *(const float2*)(g0  + c);
        const float2 g0p  = *(const float2*)(g0  + DD + c);
        const float2 be0s = *(const float2*)(be0 + c);
        const float2 be0p = *(const float2*)(be0 + DD + c);
        #pragma unroll 2
        for (int ee = 0; ee < 16; ++ee) {
            const int el = wv * 16 + ee;
            const int e  = e0 + el;
            const int u  = eidx[e];
            const int v  = eidx[NE + e];
            const float2 nu = *(const float2*)(nodes + u * DD + c);
            const float2 nv = *(const float2*)(nodes + v * DD + c);
            const float2 bu = *(const float2*)(nbrs  + u * DD + c);
            const float2 bv = *(const float2*)(nbrs  + v * DD + c);
            const float sx = nu.x + nv.x, sy = nu.y + nv.y;
            const float px = nu.x * nv.x, py = nu.y * nv.y;
            float ps  = sx + sy + px + py;
            float pss = sx*sx + sy*sy + px*px + py*py;
            float pd  = bu.x * bv.x + bu.y * bv.y;
            #pragma unroll
            for (int m = 1; m < 64; m <<= 1) {
                ps  += __shfl_xor(ps,  m, 64);
                pss += __shfl_xor(pss, m, 64);
                pd  += __shfl_xor(pd,  m, 64);
            }
            const float mu  = ps  * (1.0f / 256.0f);
            const float var = pss * (1.0f / 256.0f) - mu * mu;
            const float inv = 1.0f / sqrtf(var + EPSLN);
            *(float2*)&xb[el][c]      = make_float2((sx - mu) * inv * g0s.x + be0s.x,
                                                    (sy - mu) * inv * g0s.y + be0s.y);
            *(float2*)&xb[el][DD + c] = make_float2((px - mu) * inv * g0p.x + be0p.x,
                                                    (py - mu) * inv * g0p.y + be0p.y);
            if (lane == 0) nbsim[el] = pd;
        }
    }
    __builtin_amdgcn_wave_barrier();   // fence: stage-1 LDS writes before GEMM1 reads

    // ---------------- GEMM1: 8x8 tile, double-buffered x and W ---------------
    f32x2 acc1[8][4];
    #pragma unroll
    for (int i = 0; i < 8; ++i)
        #pragma unroll
        for (int p = 0; p < 4; ++p) acc1[i][p] = f32x2{0.0f, 0.0f};

    const int c1 = cb * 8;
    {
        const float* __restrict__ w1p = W1 + c1;
        f32x4 xA[8], wA8[8], xB[8], wB8[8];
        G1_PREF(xA, wA8, 0);
        for (int k0 = 0; k0 < TWOD; k0 += 8) {
            G1_PREF(xB, wB8, k0 + 4);
            G1_FMA(xA, wA8);
            G1_PREF(xA, wA8, k0 + 8);   // wraps to 0 on last iter: harmless
            G1_FMA(xB, wB8);
        }
    }
    __builtin_amdgcn_wave_barrier();   // fence: GEMM1 LDS reads before LN1 writes

    // ---------------- bias + LN1 + ReLU, write h1 back (own rows) ------------
    {
        const float4 b1a = *(const float4*)(b1  + c1);
        const float4 b1b = *(const float4*)(b1  + c1 + 4);
        const float4 g1a = *(const float4*)(g1  + c1);
        const float4 g1b = *(const float4*)(g1  + c1 + 4);
        const float4 e1a = *(const float4*)(be1 + c1);
        const float4 e1b = *(const float4*)(be1 + c1 + 4);
        #pragma unroll
        for (int i = 0; i < 8; ++i) {
            float v[8];
            v[0] = acc1[i][0].x + b1a.x; v[1] = acc1[i][0].y + b1a.y;
            v[2] = acc1[i][1].x + b1a.z; v[3] = acc1[i][1].y + b1a.w;
            v[4] = acc1[i][2].x + b1b.x; v[5] = acc1[i][2].y + b1b.y;
            v[6] = acc1[i][3].x + b1b.z; v[7] = acc1[i][3].y + b1b.w;
            float s = 0.0f, ss = 0.0f;
            #pragma unroll
            for (int j = 0; j < 8; ++j) { s += v[j]; ss += v[j] * v[j]; }
            #pragma unroll
            for (int m = 1; m < 32; m <<= 1) {
                s  += __shfl_xor(s,  m, 32);
                ss += __shfl_xor(ss, m, 32);
            }
            const float mu  = s  * (1.0f / 256.0f);
            const float var = ss * (1.0f / 256.0f) - mu * mu;
            const float inv = 1.0f / sqrtf(var + EPSLN);
            float o[8];
            o[0] = fmaxf(0.0f, (v[0]-mu)*inv*g1a.x + e1a.x);
            o[1] = fmaxf(0.0f, (v[1]-mu)*inv*g1a.y + e1a.y);
            o[2] = fmaxf(0.0f, (v[2]-mu)*inv*g1a.z + e1a.z);
            o[3] = fmaxf(0.0f, (v[3]-mu)*inv*g1a.w + e1a.w);
            o[4] = fmaxf(0.0f, (v[4]-mu)*inv*g1b.x + e1b.x);
            o[5] = fmaxf(0.0f, (v[5]-mu)*inv*g1b.y + e1b.y);
            o[6] = fmaxf(0.0f, (v[6]-mu)*inv*g1b.z + e1b.z);
            o[7] = fmaxf(0.0f, (v[7]-mu)*inv*g1b.w + e1b.w);
            *(float4*)&xb[r0 + i][c1]     = make_float4(o[0], o[1], o[2], o[3]);
            *(float4*)&xb[r0 + i][c1 + 4] = make_float4(o[4], o[5], o[6], o[7]);
        }
    }
    __builtin_amdgcn_wave_barrier();   // fence: LN1 writes before GEMM2 reads

    // ---------------- GEMM2: 8x4 tile, double-buffered x and W ---------------
    f32x2 acc2[8][2];
    #pragma unroll
    for (int i = 0; i < 8; ++i) {
        acc2[i][0] = f32x2{0.0f, 0.0f};
        acc2[i][1] = f32x2{0.0f, 0.0f};
    }

    const int c2 = cb * 4;
    {
        const float* __restrict__ w2p = W2 + c2;
        f32x4 xA[8], wA4[4], xB[8], wB4[4];
        G2_PREF(xA, wA4, 0);
        for (int k0 = 0; k0 < TWOD; k0 += 8) {
            G2_PREF(xB, wB4, k0 + 4);
            G2_FMA(xA, wA4);
            G2_PREF(xA, wA4, k0 + 8);   // wraps on last iter: harmless
            G2_FMA(xB, wB4);
        }
    }

    // ---------------- bias + LN2 + ReLU + heads + outputs --------------------
    {
        const float4 b2v = *(const float4*)(b2  + c2);
        const float4 g2v = *(const float4*)(g2  + c2);
        const float4 e2v = *(const float4*)(be2 + c2);
        const float4 wpv = *(const float4*)(Wp  + c2);
        const float4 wwv = *(const float4*)(Ww  + c2);
        const float ww128 = Ww[DD];
        const float bpv = bp[0], bwv = bw[0];
        const float wn = wnode[0], wbr = wnbr[0];
        #pragma unroll
        for (int i = 0; i < 8; ++i) {
            float v0 = acc2[i][0].x + b2v.x;
            float v1 = acc2[i][0].y + b2v.y;
            float v2 = acc2[i][1].x + b2v.z;
            float v3 = acc2[i][1].y + b2v.w;
            float s  = v0 + v1 + v2 + v3;
            float ss = v0*v0 + v1*v1 + v2*v2 + v3*v3;
            #pragma unroll
            for (int m = 1; m < 32; m <<= 1) {
                s  += __shfl_xor(s,  m, 32);
                ss += __shfl_xor(ss, m, 32);
            }
            const float mu  = s  * (1.0f / 128.0f);
            const float var = ss * (1.0f / 128.0f) - mu * mu;
            const float inv = 1.0f / sqrtf(var + EPSLN);
            const float h0  = fmaxf(0.0f, (v0-mu)*inv*g2v.x + e2v.x);
            const float h1v = fmaxf(0.0f, (v1-mu)*inv*g2v.y + e2v.y);
            const float h2v = fmaxf(0.0f, (v2-mu)*inv*g2v.z + e2v.z);
            const float h3  = fmaxf(0.0f, (v3-mu)*inv*g2v.w + e2v.w);
            float pdot = h0*wpv.x + h1v*wpv.y + h2v*wpv.z + h3*wpv.w;
            float wdot = h0*wwv.x + h1v*wwv.y + h2v*wwv.z + h3*wwv.w;
            #pragma unroll
            for (int m = 1; m < 32; m <<= 1) {
                pdot += __shfl_xor(pdot, m, 32);
                wdot += __shfl_xor(wdot, m, 32);
            }
            if (cb == 0) {
                const int e  = e0 + r0 + i;
                const float ns   = nbsim[r0 + i];
                const float nc   = (pdot + bpv) * wn;
                const float nbc  = ns * wbr;
                const float prob = nc + nbc;
                out[e]          = prob;
                out[NE + e]     = fmaxf(0.0f, wdot + ns * ww128 + bwv);
                out[2 * NE + e] = nc / (prob + 1e-8f);
            }
        }
    }
}

extern "C" void kernel_launch(void* const* d_in, const int* in_sizes, int n_in,
                              void* d_out, int out_size, void* d_ws, size_t ws_size,
                              hipStream_t stream) {
    const float* nodes = (const float*)d_in[0];
    const float* nbrs  = (const float*)d_in[1];
    const int*   eidx  = (const int*)d_in[2];
    const float* g0    = (const float*)d_in[3];
    const float* be0   = (const float*)d_in[4];
    const float* W1    = (const float*)d_in[5];
    const float* b1    = (const float*)d_in[6];
    const float* g1    = (const float*)d_in[7];
    const float* be1   = (const float*)d_in[8];
    const float* W2    = (const float*)d_in[9];
    const float* b2    = (const float*)d_in[10];
    const float* g2    = (const float*)d_in[11];
    const float* be2   = (const float*)d_in[12];
    const float* Wp    = (const float*)d_in[13];
    const float* bp    = (const float*)d_in[14];
    const float* Ww    = (const float*)d_in[15];
    const float* bw    = (const float*)d_in[16];
    const float* wnode = (const float*)d_in[17];
    const float* wnbr  = (const float*)d_in[18];
    float* out = (float*)d_out;

    dim3 grid(NE / EB), block(256);
    decoder_fused<<<grid, block, 0, stream>>>(nodes, nbrs, eidx, g0, be0,
                                              W1, b1, g1, be1, W2, b2, g2, be2,
                                              Wp, bp, Ww, bw, wnode, wnbr, out);
}